// Round 1
// 459.790 us; speedup vs baseline: 1.1189x; 1.1189x over previous
//
#include <hip/hip_runtime.h>

typedef __attribute__((ext_vector_type(8))) short short8;
typedef __attribute__((ext_vector_type(4))) float f32x4;

#define MAXNORM 0.996f        // (1 - 4e-3)/sqrt(c), c=1
#define MINNORM 1e-15f
#define ATEPS   (1.0f - 1e-7f)

__device__ __forceinline__ float frcp(float x) { return __builtin_amdgcn_rcpf(x); }
// artanh on [0, 1-1e-7] with the reference clamp folded in
__device__ __forceinline__ float artanh_c(float z) {
    z = fminf(z, ATEPS);
    return 0.5f * __logf((1.0f + z) * frcp(1.0f - z));
}
// tanh for a >= 0
__device__ __forceinline__ float tanh_pos(float a) {
    float e = __expf(-2.0f * a);
    return (1.0f - e) * frcp(1.0f + e);
}
// fp32 -> bf16 bits, round-to-nearest-even (bit-identical to previous kernel)
__device__ __forceinline__ unsigned short f2bf(float f) {
    union { float f; unsigned u; } v; v.f = f;
    unsigned r = v.u + 0x7FFFu + ((v.u >> 16) & 1u);
    return (unsigned short)(r >> 16);
}

// ---- prologue: pack W (fp32 [128,128]) into bf16 MFMA B-fragments ----
// Wp[(nt*4+ks)*64 + lane] = short8 { f2bf(W[nt*16+c][ks*32+q*8 + j]) }
// so the main kernel's B-fragment load is one coalesced 16B/lane read.
__global__ __launch_bounds__(256) void wpack_kernel(
    const float* __restrict__ Wf, short8* __restrict__ Wp)
{
    const int tid = blockIdx.x * 256 + threadIdx.x;   // 0..2047
    const int l = tid & 63;
    const int f = tid >> 6;        // fragment id 0..31
    const int nt = f >> 2, ks = f & 3;
    const int c = l & 15, q = l >> 4;
    const float* src = Wf + (nt * 16 + c) * 128 + ks * 32 + q * 8;
    short8 s;
    #pragma unroll
    for (int j = 0; j < 4; ++j) {
        s[j]     = (short)f2bf(src[j]);
        s[4 + j] = (short)f2bf(src[4 + j]);
    }
    Wp[tid] = s;
}

__global__ __launch_bounds__(256) void blinear_kernel(
    const float* __restrict__ Xf,   // [N,128] fp32
    const short8* __restrict__ Wp,  // [32][64] packed bf16 B-fragments (32 KB)
    const float* __restrict__ Bf,   // [128] fp32
    float* __restrict__ Out)        // [N,128] fp32
{
    const int lane = threadIdx.x & 63;
    const int wave = threadIdx.x >> 6;
    const int c = lane & 15;   // col within 16x16 tile / A-row selector
    const int q = lane >> 4;   // quad (k-group selector; row-group in C layout)
    const long rowbase = (long)blockIdx.x * 64 + wave * 16;   // 16 rows per wave

    // ---- bias prologue (per-wave, redundant, no LDS) ----
    float b0 = Bf[lane];
    float b1 = Bf[64 + lane];
    float bn2 = b0 * b0 + b1 * b1;
    #pragma unroll
    for (int m = 1; m <= 32; m <<= 1) bn2 += __shfl_xor(bn2, m);
    float bn = fmaxf(sqrtf(bn2), MINNORM);
    float tb = tanh_pos(bn);
    float fb = fminf(tb, MAXNORM) * frcp(bn);
    float hb2 = fb * fb * bn2;                 // sum(hb^2)
    float hbv[8];                              // hb at cols nt*16 + c
    #pragma unroll
    for (int nt = 0; nt < 8; ++nt) hbv[nt] = fb * Bf[nt * 16 + c];

    // ---- A fragments: X read once (fp32), packed to bf16; Sum(x^2) in fp32 ----
    short8 afr[4];
    float xq = 0.0f;
    const float* xrow = Xf + (rowbase + c) * 128;
    #pragma unroll
    for (int ks = 0; ks < 4; ++ks) {
        f32x4 a0 = *(const f32x4*)(xrow + ks * 32 + q * 8);
        f32x4 a1 = *(const f32x4*)(xrow + ks * 32 + q * 8 + 4);
        short8 s;
        #pragma unroll
        for (int j = 0; j < 4; ++j) {
            float v0 = a0[j], v1 = a1[j];
            xq = fmaf(v0, v0, fmaf(v1, v1, xq));
            s[j] = (short)f2bf(v0);
            s[4 + j] = (short)f2bf(v1);
        }
        afr[ks] = s;
    }
    // reduce Sum(x^2) across the 4 quads (each quad holds a disjoint k-range)
    xq += __shfl_xor(xq, 16);
    xq += __shfl_xor(xq, 32);
    // redistribute to C-layout row owner (row = q*4 + r)
    float xn2v[4];
    #pragma unroll
    for (int r = 0; r < 4; ++r) xn2v[r] = __shfl(xq, q * 4 + r);

    // ---- GEMM: mx = X @ W^T, 16x16x32 bf16 MFMA; B-fragments pre-packed ----
    f32x4 acc[8];
    {
        f32x4 z = {0.0f, 0.0f, 0.0f, 0.0f};
        #pragma unroll
        for (int nt = 0; nt < 8; ++nt) acc[nt] = z;
    }
    #pragma unroll
    for (int nt = 0; nt < 8; ++nt) {
        #pragma unroll
        for (int ks = 0; ks < 4; ++ks) {
            short8 bfr = Wp[(nt * 4 + ks) * 64 + lane];
            acc[nt] = __builtin_amdgcn_mfma_f32_16x16x32_bf16(afr[ks], bfr, acc[nt], 0, 0, 0);
        }
    }

    // ---- round-1 reductions over cols: mn2 = sum(mx^2), mhb = sum(mx*hb) ----
    // C layout: col = lane&15 (+16*nt), row = q*4 + reg
    float mn2[4] = {}, mhb[4] = {};
    #pragma unroll
    for (int nt = 0; nt < 8; ++nt)
        #pragma unroll
        for (int r = 0; r < 4; ++r) {
            float v = acc[nt][r];
            mn2[r] = fmaf(v, v, mn2[r]);
            mhb[r] = fmaf(v, hbv[nt], mhb[r]);
        }
    #pragma unroll
    for (int m = 1; m <= 8; m <<= 1)
        #pragma unroll
        for (int r = 0; r < 4; ++r) {
            mn2[r] += __shfl_xor(mn2[r], m);
            mhb[r] += __shfl_xor(mhb[r], m);
        }

    // ---- per-row scalar chain (each lane owns its quad's 4 rows) ----
    float A1[4], B1[4], Gg[4], S3[4];
    #pragma unroll
    for (int r = 0; r < 4; ++r) {
        float xn = fmaxf(sqrtf(xn2v[r]), MINNORM);
        float mn = fmaxf(sqrtf(mn2[r]), MINNORM);
        // mobius_matvec: res = tanh(mx_n/x_n * artanh(x_n)) * mx / mx_n, then proj
        float t1 = tanh_pos(mn * frcp(xn) * artanh_c(xn));
        float rn = fminf(t1, MAXNORM);          // ||res|| after proj
        float f1 = rn * frcp(mn);               // res = f1 * mx
        float x2 = rn * rn;
        // mobius_add(res, hb): res2 = (A*res + B*hb)/D
        float xy = f1 * mhb[r];
        float Aa = 1.0f + 2.0f * xy + hb2;
        float Bb = 1.0f - x2;
        float Dn = fmaxf(1.0f + 2.0f * xy + x2 * hb2, MINNORM);
        float rD = frcp(Dn);
        float a1 = Aa * f1 * rD;                // res2 = a1*mx + b1_*hb
        float b1_ = Bb * rD;
        float r2n2 = a1 * a1 * mn2[r] + 2.0f * a1 * b1_ * mhb[r] + b1_ * b1_ * hb2;
        float r2n = sqrtf(fmaxf(r2n2, 0.0f));
        float g = (r2n > MAXNORM) ? (MAXNORM * frcp(r2n)) : 1.0f;   // proj
        float n3 = fmaxf(fminf(r2n, MAXNORM), MINNORM);
        float s3 = artanh_c(n3) * frcp(n3);     // logmap0 scale (>0, commutes with relu)
        A1[r] = a1; B1[r] = b1_; Gg[r] = g; S3[r] = s3;
    }

    // ---- round-2 reduction: q2 = sum(max(a1*mx + b1_*hb, 0)^2) ----
    float q2[4] = {};
    #pragma unroll
    for (int nt = 0; nt < 8; ++nt)
        #pragma unroll
        for (int r = 0; r < 4; ++r) {
            float v = fmaf(A1[r], acc[nt][r], B1[r] * hbv[nt]);
            v = fmaxf(v, 0.0f);
            acc[nt][r] = v;                     // keep relu'd pre-scale value
            q2[r] = fmaf(v, v, q2[r]);
        }
    #pragma unroll
    for (int m = 1; m <= 8; m <<= 1)
        #pragma unroll
        for (int r = 0; r < 4; ++r) q2[r] += __shfl_xor(q2[r], m);

    // ---- final scale: logmap0-scale * proj-scale folded into expmap0 + proj ----
    float K[4];
    #pragma unroll
    for (int r = 0; r < 4; ++r) {
        float sg = S3[r] * Gg[r];
        float tn_t = sg * sqrtf(q2[r]);         // ||relu(logmap0(res3))||
        float tn = fmaxf(tn_t, MINNORM);
        float t4 = tanh_pos(tn);
        K[r] = fminf(t4, MAXNORM) * frcp(tn) * sg;
    }

    // ---- store: out_j = K * relu_val, fp32, nontemporal (keep Out out of L3) ----
    #pragma unroll
    for (int r = 0; r < 4; ++r) {
        long row = rowbase + q * 4 + r;
        float* orow = Out + row * 128;
        #pragma unroll
        for (int nt = 0; nt < 8; ++nt)
            __builtin_nontemporal_store(K[r] * acc[nt][r], orow + nt * 16 + c);
    }
}

extern "C" void kernel_launch(void* const* d_in, const int* in_sizes, int n_in,
                              void* d_out, int out_size, void* d_ws, size_t ws_size,
                              hipStream_t stream) {
    const float* X = (const float*)d_in[0];   // fp32 [N,128]
    const float* W = (const float*)d_in[1];   // fp32 [128,128]
    const float* B = (const float*)d_in[2];   // fp32 [128]
    float* Out = (float*)d_out;
    short8* Wp = (short8*)d_ws;               // 32 KB packed bf16 W
    const int N = in_sizes[0] / 128;          // 524288 rows
    wpack_kernel<<<8, 256, 0, stream>>>(W, Wp);
    blinear_kernel<<<N / 64, 256, 0, stream>>>(X, Wp, B, Out);   // 64 rows/block
}